// Round 13
// baseline (125.446 us; speedup 1.0000x reference)
//
#include <hip/hip_runtime.h>
#include <hip/hip_bf16.h>

#define NH   8
#define HID  256
#define VD   32
#define NQ   2048
#define NKK  2048
#define NB   16
#define NN   512   // NB*VD

typedef short bf16x8 __attribute__((ext_vector_type(8)));
typedef float f32x4 __attribute__((ext_vector_type(4)));

__device__ inline unsigned short f2bf(float f) {
  unsigned int u = __float_as_uint(f);
  u += 0x7FFFu + ((u >> 16) & 1u);   // RNE
  return (unsigned short)(u >> 16);
}

__device__ inline void gload_lds16(const void* g, void* l) {
  __builtin_amdgcn_global_load_lds(
      (const __attribute__((address_space(1))) void*)g,
      (__attribute__((address_space(3))) void*)l, 16, 0, 0);
}

__device__ inline float gelu_f(float x) {
  // jax.nn.gelu approximate: 0.5x(1+tanh(u)), tanh via exp (2u in [-20,20], no overflow)
  float u2 = 1.5957691216057308f * (x + 0.044715f * x * x * x);  // 2u
  float e = __expf(u2);
  return 0.5f * x * (1.0f + (e - 1.0f) / (e + 1.0f));
}

// LDS tile swizzle (T2): 16B slot s of row r holds logical slot s ^ ((r>>1)&3).

// ---------------- kernel 1: per-b MFMA GEMM: vT[(h,v)][k] = sum_j bf16(w[h][j][v]) * bf16(x[b][k][j])
__global__ __launch_bounds__(256) void value_kernel(
    const float* __restrict__ w, const float* __restrict__ x,
    unsigned short* __restrict__ vT) {
  const int vb  = blockIdx.x;
  const int hvt = vb & 1;              // hv tile (0..1)
  const int kt  = (vb >> 1) & 15;      // k tile (0..15)
  const int b   = vb >> 5;             // batch (0..15)
  const int m0 = hvt * 128;
  const int n0 = kt * 128;
  const int t = threadIdx.x;
  const int lane = t & 63, wid = t >> 6;
  const int wr = wid >> 1, wc = wid & 1;

  __shared__ __align__(16) unsigned short As[128 * 32];
  __shared__ __align__(16) unsigned short Bs[128 * 32];

  // A staging: strided f32 w loads, convert, swizzled ds_write
  const int arow = t >> 1;             // 0..127 (hv row)
  const int ahalf = t & 1;             // j half (16 elems)
  const int hh = (m0 + arow) >> 5, avv = (m0 + arow) & 31;
  const float* wbase = w + ((size_t)hh * HID + ahalf * 16) * VD + avv;
  const int ac = (arow >> 1) & 3;
  unsigned short* wA0 = (unsigned short*)((char*)As + arow * 64 + (((2 * ahalf) ^ ac) * 16));
  unsigned short* wA1 = (unsigned short*)((char*)As + arow * 64 + (((2 * ahalf + 1) ^ ac) * 16));

  // B staging via registers with f32->bf16 (x rows are k-cols of output)
  const int brow = t >> 1, bj = (t & 1) * 16;
  const float* gB = x + ((size_t)b * NKK + n0 + brow) * HID + bj;
  const int bc = (brow >> 1) & 3;
  const int bs0 = (2 * (t & 1)) ^ bc;          // physical 16B slot for first uint4
  unsigned short* lB0 = Bs + brow * 32 + bs0 * 8;
  unsigned short* lB1 = Bs + brow * 32 + (bs0 ^ 1) * 8;

  f32x4 acc[4][4];
#pragma unroll
  for (int i = 0; i < 4; ++i)
#pragma unroll
    for (int j = 0; j < 4; ++j) acc[i][j] = (f32x4){0.f, 0.f, 0.f, 0.f};

  const int fr = lane & 15;
  const int kb = (((lane >> 4) ^ ((fr >> 1) & 3)) * 16);   // swizzled read slot
  const char* baseA = (const char*)As + (wr * 64 + fr) * 64 + kb;
  const char* baseB = (const char*)Bs + (wc * 64 + fr) * 64 + kb;

  // prefetch B step 0
  f32x4 p0 = *(const f32x4*)(gB + 0);
  f32x4 p1 = *(const f32x4*)(gB + 4);
  f32x4 p2 = *(const f32x4*)(gB + 8);
  f32x4 p3 = *(const f32x4*)(gB + 12);

  for (int kk = 0; kk < HID / 32; ++kk) {
    // A: 16 strided f32 loads (stride 128B) from w
    float av[16];
#pragma unroll
    for (int e = 0; e < 16; ++e) av[e] = wbase[((size_t)kk * 32 + e) * VD];

    f32x4 c0 = p0, c1 = p1, c2 = p2, c3 = p3;
    if (kk < HID / 32 - 1) {
      const float* nb = gB + (kk + 1) * 32;
      p0 = *(const f32x4*)(nb + 0);
      p1 = *(const f32x4*)(nb + 4);
      p2 = *(const f32x4*)(nb + 8);
      p3 = *(const f32x4*)(nb + 12);
    }
    uint4 qa0, qa1;
    qa0.x = (unsigned)f2bf(av[0]) | ((unsigned)f2bf(av[1]) << 16);
    qa0.y = (unsigned)f2bf(av[2]) | ((unsigned)f2bf(av[3]) << 16);
    qa0.z = (unsigned)f2bf(av[4]) | ((unsigned)f2bf(av[5]) << 16);
    qa0.w = (unsigned)f2bf(av[6]) | ((unsigned)f2bf(av[7]) << 16);
    qa1.x = (unsigned)f2bf(av[8]) | ((unsigned)f2bf(av[9]) << 16);
    qa1.y = (unsigned)f2bf(av[10]) | ((unsigned)f2bf(av[11]) << 16);
    qa1.z = (unsigned)f2bf(av[12]) | ((unsigned)f2bf(av[13]) << 16);
    qa1.w = (unsigned)f2bf(av[14]) | ((unsigned)f2bf(av[15]) << 16);
    *(uint4*)wA0 = qa0;
    *(uint4*)wA1 = qa1;

    uint4 pk0, pk1;
    pk0.x = (unsigned)f2bf(c0[0]) | ((unsigned)f2bf(c0[1]) << 16);
    pk0.y = (unsigned)f2bf(c0[2]) | ((unsigned)f2bf(c0[3]) << 16);
    pk0.z = (unsigned)f2bf(c1[0]) | ((unsigned)f2bf(c1[1]) << 16);
    pk0.w = (unsigned)f2bf(c1[2]) | ((unsigned)f2bf(c1[3]) << 16);
    pk1.x = (unsigned)f2bf(c2[0]) | ((unsigned)f2bf(c2[1]) << 16);
    pk1.y = (unsigned)f2bf(c2[2]) | ((unsigned)f2bf(c2[3]) << 16);
    pk1.z = (unsigned)f2bf(c3[0]) | ((unsigned)f2bf(c3[1]) << 16);
    pk1.w = (unsigned)f2bf(c3[2]) | ((unsigned)f2bf(c3[3]) << 16);
    *(uint4*)lB0 = pk0;
    *(uint4*)lB1 = pk1;

    __syncthreads();

    bf16x8 a[4], bfr[4];
#pragma unroll
    for (int i = 0; i < 4; ++i) a[i] = *(const bf16x8*)(baseA + i * 16 * 64);
#pragma unroll
    for (int j = 0; j < 4; ++j) bfr[j] = *(const bf16x8*)(baseB + j * 16 * 64);
#pragma unroll
    for (int i = 0; i < 4; ++i)
#pragma unroll
      for (int j = 0; j < 4; ++j)
        acc[i][j] = __builtin_amdgcn_mfma_f32_16x16x32_bf16(a[i], bfr[j], acc[i][j], 0, 0, 0);
    __syncthreads();
  }

  // epilogue: C[m=hv][n=k]; D row=(lane>>4)*4+e (A-row), col=lane&15 (B-row)
  const int hvb = m0 + wr * 64 + (lane >> 4) * 4;
  const int kc0 = n0 + wc * 64 + (lane & 15);
#pragma unroll
  for (int i = 0; i < 4; ++i) {
#pragma unroll
    for (int j = 0; j < 4; ++j) {
      int kc = kc0 + j * 16;
#pragma unroll
      for (int e = 0; e < 4; ++e) {
        int hv = hvb + i * 16 + e;
        int h = hv >> 5, v = hv & 31;
        vT[((size_t)h * NN + b * VD + v) * NKK + kc] = f2bf(acc[i][j][e]);
      }
    }
  }
}

// ---------------- kernel 2: ONE WAVE PER (h,q) ROW — median stats only
// Writes (thr, minscaled) per row; exp/normalize moved into gemm (epilogue-inv).
__global__ __launch_bounds__(256) void stats_kernel(
    const float* __restrict__ m_dist, const float* __restrict__ r,
    float2* __restrict__ stats) {
  const int t = threadIdx.x;
  const int w = t >> 6;                // wave 0..3
  const int lane = t & 63;
  const int row = (blockIdx.x << 2) | w;   // h*NQ + q
  const int h = row >> 11;

  __shared__ unsigned int histS[4][260];
  __shared__ float collS[4][192];
  __shared__ unsigned int minS[4];     // uint-ordered min (values >= 0)
  __shared__ float vabS[4][2];

  unsigned int* hist = histS[w];
  float* coll = collS[w];

  const float C = (float)(0.25 * 3.141592653589793 * (1.0 - 1e-7));
  float sc = tanf(C * (1.0f + sinf(r[h])));

  *(uint4*)&hist[lane * 4] = (uint4){0u, 0u, 0u, 0u};
  if (lane == 0) minS[w] = 0xFFFFFFFFu;

  const float* md = m_dist + (size_t)row * NKK + 4 * lane;
  f32x4 m4[8];
#pragma unroll
  for (int k = 0; k < 8; ++k) m4[k] = *(const f32x4*)(md + 256 * k);

  // lane-local min: ILP tree over 32 values
  float t16[16];
#pragma unroll
  for (int i = 0; i < 16; ++i) t16[i] = fminf(m4[i >> 1][(i & 1) * 2], m4[i >> 1][(i & 1) * 2 + 1]);
#pragma unroll
  for (int s = 8; s; s >>= 1)
#pragma unroll
    for (int i = 0; i < s; ++i) t16[i] = fminf(t16[i], t16[i + s]);
  atomicMin(&minS[w], __float_as_uint(t16[0]));   // fire-and-forget; nonneg -> uint order

  // histogram (fire-and-forget LDS atomics)
#pragma unroll
  for (int k = 0; k < 8; ++k)
#pragma unroll
    for (int e = 0; e < 4; ++e) {
      int bin = min(max((int)(m4[k][e] * 256.0f), 0), 255);
      atomicAdd(&hist[bin], 1u);
    }

  asm volatile("s_waitcnt lgkmcnt(0)" ::: "memory");   // hist + min complete
  uint4 hc = *(const uint4*)&hist[lane * 4];           // lane owns bins 4l..4l+3
  unsigned c0 = hc.x, c1 = hc.x + hc.y, c2 = c1 + hc.z, c3 = c2 + hc.w;
  unsigned g = c3;
  unsigned incl = g;
#pragma unroll
  for (int off = 1; off < 64; off <<= 1) {
    unsigned y = __shfl_up(incl, off);
    if (lane >= off) incl += y;
  }
  unsigned excl = incl - g;

  // locate bin of rank 1023 (bA, below) and rank 1024 (bB)
  unsigned long long ba1 = __ballot(incl >= 1024u);
  int glA = __ffsll((unsigned long long)ba1) - 1;
  unsigned eA = __shfl(excl, glA);
  unsigned a0 = __shfl(excl + c0, glA), a1 = __shfl(excl + c1, glA), a2 = __shfl(excl + c2, glA);
  int bA; unsigned below;
  if (a0 >= 1024u)      { bA = glA * 4 + 0; below = eA; }
  else if (a1 >= 1024u) { bA = glA * 4 + 1; below = a0; }
  else if (a2 >= 1024u) { bA = glA * 4 + 2; below = a1; }
  else                  { bA = glA * 4 + 3; below = a2; }
  unsigned long long ba2 = __ballot(incl >= 1025u);
  int glB = __ffsll((unsigned long long)ba2) - 1;
  unsigned e0 = __shfl(excl + c0, glB), e1 = __shfl(excl + c1, glB), e2 = __shfl(excl + c2, glB);
  int bB = (e0 >= 1025u) ? glB * 4 : (e1 >= 1025u) ? glB * 4 + 1
                                   : (e2 >= 1025u) ? glB * 4 + 2 : glB * 4 + 3;

  // collect candidates via ballot-compaction
  const unsigned long long below_me = (lane == 0) ? 0ull : (~0ull >> (64 - lane));
  unsigned base = 0;
#pragma unroll
  for (int k = 0; k < 8; ++k)
#pragma unroll
    for (int e = 0; e < 4; ++e) {
      float v = m4[k][e];
      int bin = min(max((int)(v * 256.0f), 0), 255);
      bool pred = (bin >= bA && bin <= bB);
      unsigned long long mask = __ballot(pred);
      if (pred) {
        unsigned idx = base + (unsigned)__popcll(mask & below_me);
        if (idx < 192u) coll[idx] = v;
      }
      base += (unsigned)__popcll(mask);
    }
  const int n = (int)min(base, 192u);
  asm volatile("s_waitcnt lgkmcnt(0)" ::: "memory");

  // rank among candidates (ra/rb within window)
  const int ra = 1023 - (int)below, rb = 1024 - (int)below;
  for (int idx = lane; idx < n; idx += 64) {
    float v = coll[idx];
    int rank = 0;
    for (int j2 = 0; j2 < n; ++j2) {
      float u = coll[j2];
      rank += (u < v || (u == v && j2 < idx)) ? 1 : 0;  // stable rank
    }
    if (rank == ra) vabS[w][0] = v;
    if (rank == rb) vabS[w][1] = v;
  }
  asm volatile("s_waitcnt lgkmcnt(0)" ::: "memory");

  if (lane == 0) {
    float thr = 0.5f * (vabS[w][0] * sc) + 0.5f * (vabS[w][1] * sc);
    float ms = __uint_as_float(minS[w]) * sc;
    stats[row] = make_float2(thr, ms);
  }
}

// ---------------- kernel 3: per head GEMM with on-the-fly P = exp(ms - m*sc) [<=thr]
// C[q,n] = P[h] @ vT[h]^T ; epilogue: out = gelu(C / wsum_row). No att matrix.
__global__ __launch_bounds__(256) void gemm_kernel(
    const float* __restrict__ m_dist, const float* __restrict__ r,
    const float2* __restrict__ stats, const unsigned short* __restrict__ vT,
    float* __restrict__ out) {
  const int bid = blockIdx.x;
  const int h = bid & 7;           // XCD = bid%8; nt-blocks of one (h,qt) are XCD-adjacent
  const int tile = bid >> 3;       // 0..63
  const int qt = tile >> 2, nt = tile & 3;
  const int q0 = qt * 128, n0 = nt * 128;
  const int t = threadIdx.x;
  const int lane = t & 63, wid = t >> 6;
  const int wr = wid >> 1, wc = wid & 1;

  __shared__ __align__(16) unsigned short As[128 * 32];
  __shared__ __align__(16) unsigned short Bs[128 * 32];
  __shared__ float wsumL[256];     // [arow][ahalf]

  const float C = (float)(0.25 * 3.141592653589793 * (1.0 - 1e-7));
  const float sc = tanf(C * (1.0f + sinf(r[h])));

  // A: reg-staged f32 m_dist -> P -> bf16 swizzled ds_write (value_kernel pattern)
  const int arow = t >> 1;             // 0..127 (q row)
  const int ahalf = t & 1;             // k half (16 elems)
  const int grow = h * NQ + q0 + arow;
  const float* gA = m_dist + (size_t)grow * NKK + ahalf * 16;
  const float2 st = stats[grow];       // {thr, ms}
  const float thr = st.x, ms = st.y;
  const int ac = (arow >> 1) & 3;
  unsigned short* wA0 = (unsigned short*)((char*)As + arow * 64 + (((2 * ahalf) ^ ac) * 16));
  unsigned short* wA1 = (unsigned short*)((char*)As + arow * 64 + (((2 * ahalf + 1) ^ ac) * 16));

  // B staging via gload_lds (vT bf16, K-contig); source k pre-swizzled
  const int rowL = t >> 2;
  const int cb = (((t & 3) ^ ((t >> 3) & 3)) * 8);
  const unsigned short* gB0 = vT + ((size_t)h * NN + n0 + rowL) * NKK + cb;
  const unsigned short* gB1 = gB0 + (size_t)64 * NKK;
  char* lB0 = (char*)Bs + t * 16;
  char* lB1 = (char*)Bs + 4096 + t * 16;

  f32x4 acc[4][4];
#pragma unroll
  for (int i = 0; i < 4; ++i)
#pragma unroll
    for (int j = 0; j < 4; ++j) acc[i][j] = (f32x4){0.f, 0.f, 0.f, 0.f};

  const int fr = lane & 15;
  const int kb = (((lane >> 4) ^ ((fr >> 1) & 3)) * 16);   // swizzled read slot
  const char* baseA = (const char*)As + (wr * 64 + fr) * 64 + kb;
  const char* baseB = (const char*)Bs + (wc * 64 + fr) * 64 + kb;

  float psum = 0.f;

  // prefetch A step 0 (16 contiguous f32)
  f32x4 p0 = *(const f32x4*)(gA + 0);
  f32x4 p1 = *(const f32x4*)(gA + 4);
  f32x4 p2 = *(const f32x4*)(gA + 8);
  f32x4 p3 = *(const f32x4*)(gA + 12);

  for (int kt = 0; kt < NKK / 32; ++kt) {
    gload_lds16(gB0, lB0);
    gload_lds16(gB1, lB1);
    gB0 += 32; gB1 += 32;

    f32x4 c0 = p0, c1 = p1, c2 = p2, c3 = p3;
    if (kt < NKK / 32 - 1) {
      const float* nb = gA + (kt + 1) * 32;
      p0 = *(const f32x4*)(nb + 0);
      p1 = *(const f32x4*)(nb + 4);
      p2 = *(const f32x4*)(nb + 8);
      p3 = *(const f32x4*)(nb + 12);
    }
    // P = (m*sc <= thr) ? exp(ms - m*sc) : 0 ; accumulate psum
    float pv[16];
#pragma unroll
    for (int e = 0; e < 4; ++e) {
      float s0 = c0[e] * sc; pv[e]      = (s0 <= thr) ? __expf(ms - s0) : 0.f;
      float s1 = c1[e] * sc; pv[4 + e]  = (s1 <= thr) ? __expf(ms - s1) : 0.f;
      float s2 = c2[e] * sc; pv[8 + e]  = (s2 <= thr) ? __expf(ms - s2) : 0.f;
      float s3 = c3[e] * sc; pv[12 + e] = (s3 <= thr) ? __expf(ms - s3) : 0.f;
    }
#pragma unroll
    for (int e = 0; e < 16; ++e) psum += pv[e];

    uint4 qa0, qa1;
    qa0.x = (unsigned)f2bf(pv[0]) | ((unsigned)f2bf(pv[1]) << 16);
    qa0.y = (unsigned)f2bf(pv[2]) | ((unsigned)f2bf(pv[3]) << 16);
    qa0.z = (unsigned)f2bf(pv[4]) | ((unsigned)f2bf(pv[5]) << 16);
    qa0.w = (unsigned)f2bf(pv[6]) | ((unsigned)f2bf(pv[7]) << 16);
    qa1.x = (unsigned)f2bf(pv[8]) | ((unsigned)f2bf(pv[9]) << 16);
    qa1.y = (unsigned)f2bf(pv[10]) | ((unsigned)f2bf(pv[11]) << 16);
    qa1.z = (unsigned)f2bf(pv[12]) | ((unsigned)f2bf(pv[13]) << 16);
    qa1.w = (unsigned)f2bf(pv[14]) | ((unsigned)f2bf(pv[15]) << 16);
    *(uint4*)wA0 = qa0;
    *(uint4*)wA1 = qa1;

    __syncthreads();   // drains vmcnt (gload_lds) + lgkm (ds_write)

    bf16x8 a[4], bfr[4];
#pragma unroll
    for (int i = 0; i < 4; ++i) a[i] = *(const bf16x8*)(baseA + i * 16 * 64);
#pragma unroll
    for (int j = 0; j < 4; ++j) bfr[j] = *(const bf16x8*)(baseB + j * 16 * 64);
#pragma unroll
    for (int i = 0; i < 4; ++i)
#pragma unroll
      for (int j = 0; j < 4; ++j)
        acc[i][j] = __builtin_amdgcn_mfma_f32_16x16x32_bf16(a[i], bfr[j], acc[i][j], 0, 0, 0);
    __syncthreads();
  }

  // deterministic per-row wsum: two partials per row
  wsumL[arow * 2 + ahalf] = psum;
  __syncthreads();

  // epilogue: D row=(lane>>4)*4+reg (q), col=lane&15 (n); out[b, q, h*32+v] = gelu(C*inv)
  const int lrow0 = wr * 64 + (lane >> 4) * 4;
  const int orow = q0 + lrow0;
  const int ocol0 = n0 + wc * 64 + (lane & 15);
#pragma unroll
  for (int i = 0; i < 4; ++i) {
#pragma unroll
    for (int j = 0; j < 4; ++j) {
      int ncol = ocol0 + j * 16;
      int bb = ncol >> 5, vv = ncol & 31;
      float* op = out + ((size_t)bb * NQ + orow + i * 16) * HID + h * VD + vv;
#pragma unroll
      for (int e = 0; e < 4; ++e) {
        int lr = lrow0 + i * 16 + e;
        float inv = 1.0f / (wsumL[lr * 2] + wsumL[lr * 2 + 1]);
        op[(size_t)e * HID] = gelu_f(acc[i][j][e] * inv);
      }
    }
  }
}

extern "C" void kernel_launch(void* const* d_in, const int* in_sizes, int n_in,
                              void* d_out, int out_size, void* d_ws, size_t ws_size,
                              hipStream_t stream) {
  const float* m_dist = (const float*)d_in[0];  // [8,2048,2048]
  const float* x      = (const float*)d_in[1];  // [16,2048,256]
  const float* r      = (const float*)d_in[2];  // [8]
  const float* weight = (const float*)d_in[3];  // [8,256,32]
  float* out = (float*)d_out;                   // [16,2048,256]

  // workspace: vT bf16 (16.8 MB) + stats float2 (128 KB)
  unsigned short* vT = (unsigned short*)d_ws;
  float2* stats = (float2*)((char*)d_ws + (size_t)NH * NN * NKK * 2);

  value_kernel<<<dim3(512), dim3(256), 0, stream>>>(weight, x, vT);
  stats_kernel<<<dim3(NH * NQ / 4), dim3(256), 0, stream>>>(m_dist, r, stats);
  gemm_kernel<<<dim3(NH * 64), dim3(256), 0, stream>>>(m_dist, r, stats, vT, out);
}

// Round 14
// 125.419 us; speedup vs baseline: 1.0002x; 1.0002x over previous
//
#include <hip/hip_runtime.h>
#include <hip/hip_bf16.h>

#define NH   8
#define HID  256
#define VD   32
#define NQ   2048
#define NKK  2048
#define NB   16
#define NN   512   // NB*VD

typedef short bf16x8 __attribute__((ext_vector_type(8)));
typedef float f32x4 __attribute__((ext_vector_type(4)));

__device__ inline unsigned short f2bf(float f) {
  unsigned int u = __float_as_uint(f);
  u += 0x7FFFu + ((u >> 16) & 1u);   // RNE
  return (unsigned short)(u >> 16);
}

__device__ inline void gload_lds16(const void* g, void* l) {
  __builtin_amdgcn_global_load_lds(
      (const __attribute__((address_space(1))) void*)g,
      (__attribute__((address_space(3))) void*)l, 16, 0, 0);
}

__device__ inline float gelu_f(float x) {
  // jax.nn.gelu approximate: 0.5x(1+tanh(u)), tanh via exp (2u in [-20,20], no overflow)
  float u2 = 1.5957691216057308f * (x + 0.044715f * x * x * x);  // 2u
  float e = __expf(u2);
  return 0.5f * x * (1.0f + (e - 1.0f) / (e + 1.0f));
}

// LDS tile swizzle (T2): 16B slot s of row r holds logical slot s ^ ((r>>1)&3).

// ---------------- kernel 1: per-b MFMA GEMM: vT[(h,v)][k] = sum_j bf16(w[h][j][v]) * bf16(x[b][k][j])
__global__ __launch_bounds__(256) void value_kernel(
    const float* __restrict__ w, const float* __restrict__ x,
    unsigned short* __restrict__ vT) {
  const int vb  = blockIdx.x;
  const int hvt = vb & 1;              // hv tile (0..1)
  const int kt  = (vb >> 1) & 15;      // k tile (0..15)
  const int b   = vb >> 5;             // batch (0..15)
  const int m0 = hvt * 128;
  const int n0 = kt * 128;
  const int t = threadIdx.x;
  const int lane = t & 63, wid = t >> 6;
  const int wr = wid >> 1, wc = wid & 1;

  __shared__ __align__(16) unsigned short As[128 * 32];
  __shared__ __align__(16) unsigned short Bs[128 * 32];

  // A staging: strided f32 w loads, convert, swizzled ds_write
  const int arow = t >> 1;             // 0..127 (hv row)
  const int ahalf = t & 1;             // j half (16 elems)
  const int hh = (m0 + arow) >> 5, avv = (m0 + arow) & 31;
  const float* wbase = w + ((size_t)hh * HID + ahalf * 16) * VD + avv;
  const int ac = (arow >> 1) & 3;
  unsigned short* wA0 = (unsigned short*)((char*)As + arow * 64 + (((2 * ahalf) ^ ac) * 16));
  unsigned short* wA1 = (unsigned short*)((char*)As + arow * 64 + (((2 * ahalf + 1) ^ ac) * 16));

  // B staging via registers with f32->bf16 (x rows are k-cols of output)
  const int brow = t >> 1, bj = (t & 1) * 16;
  const float* gB = x + ((size_t)b * NKK + n0 + brow) * HID + bj;
  const int bc = (brow >> 1) & 3;
  const int bs0 = (2 * (t & 1)) ^ bc;          // physical 16B slot for first uint4
  unsigned short* lB0 = Bs + brow * 32 + bs0 * 8;
  unsigned short* lB1 = Bs + brow * 32 + (bs0 ^ 1) * 8;

  f32x4 acc[4][4];
#pragma unroll
  for (int i = 0; i < 4; ++i)
#pragma unroll
    for (int j = 0; j < 4; ++j) acc[i][j] = (f32x4){0.f, 0.f, 0.f, 0.f};

  const int fr = lane & 15;
  const int kb = (((lane >> 4) ^ ((fr >> 1) & 3)) * 16);   // swizzled read slot
  const char* baseA = (const char*)As + (wr * 64 + fr) * 64 + kb;
  const char* baseB = (const char*)Bs + (wc * 64 + fr) * 64 + kb;

  // prefetch B step 0
  f32x4 p0 = *(const f32x4*)(gB + 0);
  f32x4 p1 = *(const f32x4*)(gB + 4);
  f32x4 p2 = *(const f32x4*)(gB + 8);
  f32x4 p3 = *(const f32x4*)(gB + 12);

  for (int kk = 0; kk < HID / 32; ++kk) {
    // A: 16 strided f32 loads (stride 128B) from w
    float av[16];
#pragma unroll
    for (int e = 0; e < 16; ++e) av[e] = wbase[((size_t)kk * 32 + e) * VD];

    f32x4 c0 = p0, c1 = p1, c2 = p2, c3 = p3;
    if (kk < HID / 32 - 1) {
      const float* nb = gB + (kk + 1) * 32;
      p0 = *(const f32x4*)(nb + 0);
      p1 = *(const f32x4*)(nb + 4);
      p2 = *(const f32x4*)(nb + 8);
      p3 = *(const f32x4*)(nb + 12);
    }
    uint4 qa0, qa1;
    qa0.x = (unsigned)f2bf(av[0]) | ((unsigned)f2bf(av[1]) << 16);
    qa0.y = (unsigned)f2bf(av[2]) | ((unsigned)f2bf(av[3]) << 16);
    qa0.z = (unsigned)f2bf(av[4]) | ((unsigned)f2bf(av[5]) << 16);
    qa0.w = (unsigned)f2bf(av[6]) | ((unsigned)f2bf(av[7]) << 16);
    qa1.x = (unsigned)f2bf(av[8]) | ((unsigned)f2bf(av[9]) << 16);
    qa1.y = (unsigned)f2bf(av[10]) | ((unsigned)f2bf(av[11]) << 16);
    qa1.z = (unsigned)f2bf(av[12]) | ((unsigned)f2bf(av[13]) << 16);
    qa1.w = (unsigned)f2bf(av[14]) | ((unsigned)f2bf(av[15]) << 16);
    *(uint4*)wA0 = qa0;
    *(uint4*)wA1 = qa1;

    uint4 pk0, pk1;
    pk0.x = (unsigned)f2bf(c0[0]) | ((unsigned)f2bf(c0[1]) << 16);
    pk0.y = (unsigned)f2bf(c0[2]) | ((unsigned)f2bf(c0[3]) << 16);
    pk0.z = (unsigned)f2bf(c1[0]) | ((unsigned)f2bf(c1[1]) << 16);
    pk0.w = (unsigned)f2bf(c1[2]) | ((unsigned)f2bf(c1[3]) << 16);
    pk1.x = (unsigned)f2bf(c2[0]) | ((unsigned)f2bf(c2[1]) << 16);
    pk1.y = (unsigned)f2bf(c2[2]) | ((unsigned)f2bf(c2[3]) << 16);
    pk1.z = (unsigned)f2bf(c3[0]) | ((unsigned)f2bf(c3[1]) << 16);
    pk1.w = (unsigned)f2bf(c3[2]) | ((unsigned)f2bf(c3[3]) << 16);
    *(uint4*)lB0 = pk0;
    *(uint4*)lB1 = pk1;

    __syncthreads();

    bf16x8 a[4], bfr[4];
#pragma unroll
    for (int i = 0; i < 4; ++i) a[i] = *(const bf16x8*)(baseA + i * 16 * 64);
#pragma unroll
    for (int j = 0; j < 4; ++j) bfr[j] = *(const bf16x8*)(baseB + j * 16 * 64);
#pragma unroll
    for (int i = 0; i < 4; ++i)
#pragma unroll
      for (int j = 0; j < 4; ++j)
        acc[i][j] = __builtin_amdgcn_mfma_f32_16x16x32_bf16(a[i], bfr[j], acc[i][j], 0, 0, 0);
    __syncthreads();
  }

  // epilogue: C[m=hv][n=k]; D row=(lane>>4)*4+e (A-row), col=lane&15 (B-row)
  const int hvb = m0 + wr * 64 + (lane >> 4) * 4;
  const int kc0 = n0 + wc * 64 + (lane & 15);
#pragma unroll
  for (int i = 0; i < 4; ++i) {
#pragma unroll
    for (int j = 0; j < 4; ++j) {
      int kc = kc0 + j * 16;
#pragma unroll
      for (int e = 0; e < 4; ++e) {
        int hv = hvb + i * 16 + e;
        int h = hv >> 5, v = hv & 31;
        vT[((size_t)h * NN + b * VD + v) * NKK + kc] = f2bf(acc[i][j][e]);
      }
    }
  }
}

// ---------------- kernel 2: ONE WAVE PER (h,q) ROW — median stats only
// Writes (thr, minscaled) per row; exp/normalize moved into gemm (epilogue-inv).
__global__ __launch_bounds__(256) void stats_kernel(
    const float* __restrict__ m_dist, const float* __restrict__ r,
    float2* __restrict__ stats) {
  const int t = threadIdx.x;
  const int w = t >> 6;                // wave 0..3
  const int lane = t & 63;
  const int row = (blockIdx.x << 2) | w;   // h*NQ + q
  const int h = row >> 11;

  __shared__ unsigned int histS[4][260];
  __shared__ float collS[4][192];
  __shared__ unsigned int minS[4];     // uint-ordered min (values >= 0)
  __shared__ float vabS[4][2];

  unsigned int* hist = histS[w];
  float* coll = collS[w];

  const float C = (float)(0.25 * 3.141592653589793 * (1.0 - 1e-7));
  float sc = tanf(C * (1.0f + sinf(r[h])));

  *(uint4*)&hist[lane * 4] = (uint4){0u, 0u, 0u, 0u};
  if (lane == 0) minS[w] = 0xFFFFFFFFu;

  const float* md = m_dist + (size_t)row * NKK + 4 * lane;
  f32x4 m4[8];
#pragma unroll
  for (int k = 0; k < 8; ++k) m4[k] = *(const f32x4*)(md + 256 * k);

  // lane-local min: ILP tree over 32 values
  float t16[16];
#pragma unroll
  for (int i = 0; i < 16; ++i) t16[i] = fminf(m4[i >> 1][(i & 1) * 2], m4[i >> 1][(i & 1) * 2 + 1]);
#pragma unroll
  for (int s = 8; s; s >>= 1)
#pragma unroll
    for (int i = 0; i < s; ++i) t16[i] = fminf(t16[i], t16[i + s]);
  atomicMin(&minS[w], __float_as_uint(t16[0]));   // fire-and-forget; nonneg -> uint order

  // histogram (fire-and-forget LDS atomics)
#pragma unroll
  for (int k = 0; k < 8; ++k)
#pragma unroll
    for (int e = 0; e < 4; ++e) {
      int bin = min(max((int)(m4[k][e] * 256.0f), 0), 255);
      atomicAdd(&hist[bin], 1u);
    }

  asm volatile("s_waitcnt lgkmcnt(0)" ::: "memory");   // hist + min complete
  uint4 hc = *(const uint4*)&hist[lane * 4];           // lane owns bins 4l..4l+3
  unsigned c0 = hc.x, c1 = hc.x + hc.y, c2 = c1 + hc.z, c3 = c2 + hc.w;
  unsigned g = c3;
  unsigned incl = g;
#pragma unroll
  for (int off = 1; off < 64; off <<= 1) {
    unsigned y = __shfl_up(incl, off);
    if (lane >= off) incl += y;
  }
  unsigned excl = incl - g;

  // locate bin of rank 1023 (bA, below) and rank 1024 (bB)
  unsigned long long ba1 = __ballot(incl >= 1024u);
  int glA = __ffsll((unsigned long long)ba1) - 1;
  unsigned eA = __shfl(excl, glA);
  unsigned a0 = __shfl(excl + c0, glA), a1 = __shfl(excl + c1, glA), a2 = __shfl(excl + c2, glA);
  int bA; unsigned below;
  if (a0 >= 1024u)      { bA = glA * 4 + 0; below = eA; }
  else if (a1 >= 1024u) { bA = glA * 4 + 1; below = a0; }
  else if (a2 >= 1024u) { bA = glA * 4 + 2; below = a1; }
  else                  { bA = glA * 4 + 3; below = a2; }
  unsigned long long ba2 = __ballot(incl >= 1025u);
  int glB = __ffsll((unsigned long long)ba2) - 1;
  unsigned e0 = __shfl(excl + c0, glB), e1 = __shfl(excl + c1, glB), e2 = __shfl(excl + c2, glB);
  int bB = (e0 >= 1025u) ? glB * 4 : (e1 >= 1025u) ? glB * 4 + 1
                                   : (e2 >= 1025u) ? glB * 4 + 2 : glB * 4 + 3;

  // collect candidates via ballot-compaction
  const unsigned long long below_me = (lane == 0) ? 0ull : (~0ull >> (64 - lane));
  unsigned base = 0;
#pragma unroll
  for (int k = 0; k < 8; ++k)
#pragma unroll
    for (int e = 0; e < 4; ++e) {
      float v = m4[k][e];
      int bin = min(max((int)(v * 256.0f), 0), 255);
      bool pred = (bin >= bA && bin <= bB);
      unsigned long long mask = __ballot(pred);
      if (pred) {
        unsigned idx = base + (unsigned)__popcll(mask & below_me);
        if (idx < 192u) coll[idx] = v;
      }
      base += (unsigned)__popcll(mask);
    }
  const int n = (int)min(base, 192u);
  asm volatile("s_waitcnt lgkmcnt(0)" ::: "memory");

  // rank among candidates (ra/rb within window)
  const int ra = 1023 - (int)below, rb = 1024 - (int)below;
  for (int idx = lane; idx < n; idx += 64) {
    float v = coll[idx];
    int rank = 0;
    for (int j2 = 0; j2 < n; ++j2) {
      float u = coll[j2];
      rank += (u < v || (u == v && j2 < idx)) ? 1 : 0;  // stable rank
    }
    if (rank == ra) vabS[w][0] = v;
    if (rank == rb) vabS[w][1] = v;
  }
  asm volatile("s_waitcnt lgkmcnt(0)" ::: "memory");

  if (lane == 0) {
    float thr = 0.5f * (vabS[w][0] * sc) + 0.5f * (vabS[w][1] * sc);
    float ms = __uint_as_float(minS[w]) * sc;
    stats[row] = make_float2(thr, ms);
  }
}

// ---------------- kernel 3: per head GEMM with on-the-fly P = exp(ms - m*sc) [<=thr]
// C[q,n] = P[h] @ vT[h]^T ; epilogue: out = gelu(C / wsum_row). No att matrix.
__global__ __launch_bounds__(256) void gemm_kernel(
    const float* __restrict__ m_dist, const float* __restrict__ r,
    const float2* __restrict__ stats, const unsigned short* __restrict__ vT,
    float* __restrict__ out) {
  const int bid = blockIdx.x;
  const int h = bid & 7;           // XCD = bid%8; nt-blocks of one (h,qt) are XCD-adjacent
  const int tile = bid >> 3;       // 0..63
  const int qt = tile >> 2, nt = tile & 3;
  const int q0 = qt * 128, n0 = nt * 128;
  const int t = threadIdx.x;
  const int lane = t & 63, wid = t >> 6;
  const int wr = wid >> 1, wc = wid & 1;

  __shared__ __align__(16) unsigned short As[128 * 32];
  __shared__ __align__(16) unsigned short Bs[128 * 32];
  __shared__ float wsumL[256];     // [arow][ahalf]

  const float C = (float)(0.25 * 3.141592653589793 * (1.0 - 1e-7));
  const float sc = tanf(C * (1.0f + sinf(r[h])));

  // A: reg-staged f32 m_dist -> P -> bf16 swizzled ds_write (value_kernel pattern)
  const int arow = t >> 1;             // 0..127 (q row)
  const int ahalf = t & 1;             // k half (16 elems)
  const int grow = h * NQ + q0 + arow;
  const float* gA = m_dist + (size_t)grow * NKK + ahalf * 16;
  const float2 st = stats[grow];       // {thr, ms}
  const float thr = st.x, ms = st.y;
  const int ac = (arow >> 1) & 3;
  unsigned short* wA0 = (unsigned short*)((char*)As + arow * 64 + (((2 * ahalf) ^ ac) * 16));
  unsigned short* wA1 = (unsigned short*)((char*)As + arow * 64 + (((2 * ahalf + 1) ^ ac) * 16));

  // B staging via gload_lds (vT bf16, K-contig); source k pre-swizzled
  const int rowL = t >> 2;
  const int cb = (((t & 3) ^ ((t >> 3) & 3)) * 8);
  const unsigned short* gB0 = vT + ((size_t)h * NN + n0 + rowL) * NKK + cb;
  const unsigned short* gB1 = gB0 + (size_t)64 * NKK;
  char* lB0 = (char*)Bs + t * 16;
  char* lB1 = (char*)Bs + 4096 + t * 16;

  f32x4 acc[4][4];
#pragma unroll
  for (int i = 0; i < 4; ++i)
#pragma unroll
    for (int j = 0; j < 4; ++j) acc[i][j] = (f32x4){0.f, 0.f, 0.f, 0.f};

  const int fr = lane & 15;
  const int kb = (((lane >> 4) ^ ((fr >> 1) & 3)) * 16);   // swizzled read slot
  const char* baseA = (const char*)As + (wr * 64 + fr) * 64 + kb;
  const char* baseB = (const char*)Bs + (wc * 64 + fr) * 64 + kb;

  float psum = 0.f;

  // prefetch A step 0 (16 contiguous f32)
  f32x4 p0 = *(const f32x4*)(gA + 0);
  f32x4 p1 = *(const f32x4*)(gA + 4);
  f32x4 p2 = *(const f32x4*)(gA + 8);
  f32x4 p3 = *(const f32x4*)(gA + 12);

  for (int kt = 0; kt < NKK / 32; ++kt) {
    gload_lds16(gB0, lB0);
    gload_lds16(gB1, lB1);
    gB0 += 32; gB1 += 32;

    f32x4 c0 = p0, c1 = p1, c2 = p2, c3 = p3;
    if (kt < NKK / 32 - 1) {
      const float* nb = gA + (kt + 1) * 32;
      p0 = *(const f32x4*)(nb + 0);
      p1 = *(const f32x4*)(nb + 4);
      p2 = *(const f32x4*)(nb + 8);
      p3 = *(const f32x4*)(nb + 12);
    }
    // P = (m*sc <= thr) ? exp(ms - m*sc) : 0 ; accumulate psum
    float pv[16];
#pragma unroll
    for (int e = 0; e < 4; ++e) {
      float s0 = c0[e] * sc; pv[e]      = (s0 <= thr) ? __expf(ms - s0) : 0.f;
      float s1 = c1[e] * sc; pv[4 + e]  = (s1 <= thr) ? __expf(ms - s1) : 0.f;
      float s2 = c2[e] * sc; pv[8 + e]  = (s2 <= thr) ? __expf(ms - s2) : 0.f;
      float s3 = c3[e] * sc; pv[12 + e] = (s3 <= thr) ? __expf(ms - s3) : 0.f;
    }
#pragma unroll
    for (int e = 0; e < 16; ++e) psum += pv[e];

    uint4 qa0, qa1;
    qa0.x = (unsigned)f2bf(pv[0]) | ((unsigned)f2bf(pv[1]) << 16);
    qa0.y = (unsigned)f2bf(pv[2]) | ((unsigned)f2bf(pv[3]) << 16);
    qa0.z = (unsigned)f2bf(pv[4]) | ((unsigned)f2bf(pv[5]) << 16);
    qa0.w = (unsigned)f2bf(pv[6]) | ((unsigned)f2bf(pv[7]) << 16);
    qa1.x = (unsigned)f2bf(pv[8]) | ((unsigned)f2bf(pv[9]) << 16);
    qa1.y = (unsigned)f2bf(pv[10]) | ((unsigned)f2bf(pv[11]) << 16);
    qa1.z = (unsigned)f2bf(pv[12]) | ((unsigned)f2bf(pv[13]) << 16);
    qa1.w = (unsigned)f2bf(pv[14]) | ((unsigned)f2bf(pv[15]) << 16);
    *(uint4*)wA0 = qa0;
    *(uint4*)wA1 = qa1;

    __syncthreads();   // drains vmcnt (gload_lds) + lgkm (ds_write)

    bf16x8 a[4], bfr[4];
#pragma unroll
    for (int i = 0; i < 4; ++i) a[i] = *(const bf16x8*)(baseA + i * 16 * 64);
#pragma unroll
    for (int j = 0; j < 4; ++j) bfr[j] = *(const bf16x8*)(baseB + j * 16 * 64);
#pragma unroll
    for (int i = 0; i < 4; ++i)
#pragma unroll
      for (int j = 0; j < 4; ++j)
        acc[i][j] = __builtin_amdgcn_mfma_f32_16x16x32_bf16(a[i], bfr[j], acc[i][j], 0, 0, 0);
    __syncthreads();
  }

  // deterministic per-row wsum: two partials per row
  wsumL[arow * 2 + ahalf] = psum;
  __syncthreads();

  // epilogue: D row=(lane>>4)*4+reg (q), col=lane&15 (n); out[b, q, h*32+v] = gelu(C*inv)
  const int lrow0 = wr * 64 + (lane >> 4) * 4;
  const int orow = q0 + lrow0;
  const int ocol0 = n0 + wc * 64 + (lane & 15);
#pragma unroll
  for (int i = 0; i < 4; ++i) {
#pragma unroll
    for (int j = 0; j < 4; ++j) {
      int ncol = ocol0 + j * 16;
      int bb = ncol >> 5, vv = ncol & 31;
      float* op = out + ((size_t)bb * NQ + orow + i * 16) * HID + h * VD + vv;
#pragma unroll
      for (int e = 0; e < 4; ++e) {
        int lr = lrow0 + i * 16 + e;
        float inv = 1.0f / (wsumL[lr * 2] + wsumL[lr * 2 + 1]);
        op[(size_t)e * HID] = gelu_f(acc[i][j][e] * inv);
      }
    }
  }
}

extern "C" void kernel_launch(void* const* d_in, const int* in_sizes, int n_in,
                              void* d_out, int out_size, void* d_ws, size_t ws_size,
                              hipStream_t stream) {
  const float* m_dist = (const float*)d_in[0];  // [8,2048,2048]
  const float* x      = (const float*)d_in[1];  // [16,2048,256]
  const float* r      = (const float*)d_in[2];  // [8]
  const float* weight = (const float*)d_in[3];  // [8,256,32]
  float* out = (float*)d_out;                   // [16,2048,256]

  // workspace: vT bf16 (16.8 MB) + stats float2 (128 KB)
  unsigned short* vT = (unsigned short*)d_ws;
  float2* stats = (float2*)((char*)d_ws + (size_t)NH * NN * NKK * 2);

  value_kernel<<<dim3(512), dim3(256), 0, stream>>>(weight, x, vT);
  stats_kernel<<<dim3(NH * NQ / 4), dim3(256), 0, stream>>>(m_dist, r, stats);
  gemm_kernel<<<dim3(NH * 64), dim3(256), 0, stream>>>(m_dist, r, stats, vT, out);
}